// Round 9
// baseline (124.032 us; speedup 1.0000x reference)
//
#include <hip/hip_runtime.h>
#include <hip/hip_bf16.h>

typedef __bf16 bf16_t;
typedef __attribute__((ext_vector_type(8))) __bf16 bf16x8;
typedef __attribute__((ext_vector_type(4))) float f32x4;

#define SEQ    2048
#define DMODEL 1024
#define DPROJ  256
#define NBATCH 4

__device__ __forceinline__ bf16x8 cvt8(const float4& lo, const float4& hi) {
    bf16x8 v;
    v[0] = (bf16_t)lo.x; v[1] = (bf16_t)lo.y; v[2] = (bf16_t)lo.z; v[3] = (bf16_t)lo.w;
    v[4] = (bf16_t)hi.x; v[5] = (bf16_t)hi.y; v[6] = (bf16_t)hi.z; v[7] = (bf16_t)hi.w;
    return v;
}

// async global->LDS, 16 bytes per lane. LDS dest = wave-uniform base + lane*16.
__device__ __forceinline__ void gl_lds16(const void* g, void* l) {
    __builtin_amdgcn_global_load_lds(
        (const __attribute__((address_space(1))) unsigned int*)g,
        (__attribute__((address_space(3))) unsigned int*)l, 16, 0, 0);
}

// ---------------------------------------------------------------------------
// Kernel 1 v7: H[m,p] = relu(sum_d X[m,d]*W[p,d] + b[p]).
// TRAFFIC REDESIGN (schedule experiments R2-R8 all neutral -> proj is
// BW-bound, not latency-bound):
//   Old: 512 blocks, each X-tile read by 4 N-blocks; ALL blocks co-resident
//   (2/CU x 256CU = 512, zero turnover) -> per-XCD working set = 16 X-tiles
//   (4MB) + W (1MB) = 5MB > 4MB L2 -> thrash -> X fetched ~4x from HBM
//   = ~134MB = ~22us (matches measured ~23). Also explains R4 (+9: N-fast
//   grid scattered sharers across XCDs) and R5 (+6.6: 8 sharers).
//   New: BN=256 (full W per block), BM=32 -> X read EXACTLY ONCE from HBM
//   (33.5MB) independent of L2 behavior; W (1MB) is L2-hot (~8MB HBM
//   first-touch). Floor ~6us HBM + ~7us W-L2 stream.
// Geometry: grid 256 (1 block/CU), 256 thr, 4 waves; each wave owns
// 32x64 (wn = wave*64): 2 M-frags x 4 N-frags = 32 acc VGPR.
// Staging/kt: X 256 chunks (1/thread) + W 2048 chunks (8/thread), fp32
// float4 pairs -> cvt8 -> swizzled LDS. Distance-2 prefetch (36 float4 =
// 144 VGPR; 1 block/CU so no 128 cliff). LDS: dbuf (X 4KB + W 32KB) = 72KB.
// Schedule: single-__syncthreads dbuf (verified correct R7/R8, neutral perf).
// ---------------------------------------------------------------------------
__global__ __launch_bounds__(256, 1) void proj_kernel(
    const float* __restrict__ X, const float* __restrict__ W,
    const float* __restrict__ bias, bf16_t* __restrict__ H)
{
    __shared__ __align__(16) bf16_t Xs[2][32 * 64];    // 2 x 4 KB
    __shared__ __align__(16) bf16_t Ws[2][256 * 64];   // 2 x 32 KB

    const int m0 = blockIdx.x * 32;
    const int tid  = threadIdx.x;
    const int lane = tid & 63;
    const int wave = tid >> 6;
    const int quad = lane >> 4;
    const int l16  = lane & 15;
    const int wn   = wave * 64;        // each wave: rows 0..31, cols wn..wn+63
    const int swz  = l16 & 7;

    // X staging: 256 chunks, 1 per thread
    const int xrow = tid >> 3;         // 0..31
    const int xcol = tid & 7;
    const int xoff = xrow * 64 + ((xcol ^ (xrow & 7)) * 8);
    // W staging: 2048 chunks, 8 per thread
    int wrow[8], wcol[8], woff[8];
    #pragma unroll
    for (int r = 0; r < 8; ++r) {
        const int p = r * 256 + tid;
        wrow[r] = p >> 3;              // 0..255
        wcol[r] = p & 7;
        woff[r] = wrow[r] * 64 + ((wcol[r] ^ (wrow[r] & 7)) * 8);
    }

    float4 xr[2][2];      // [stage][half]
    float4 wr[2][8][2];   // [stage][r][half]

    // prologue: preload kt=0 and kt=1 (distance-2)
    #pragma unroll
    for (int s = 0; s < 2; ++s) {
        const int k0 = s * 64;
        const float* gx = X + (size_t)(m0 + xrow) * DMODEL + k0 + xcol * 8;
        xr[s][0] = *(const float4*)gx;
        xr[s][1] = *(const float4*)(gx + 4);
        #pragma unroll
        for (int r = 0; r < 8; ++r) {
            const float* gw = W + (size_t)wrow[r] * DMODEL + k0 + wcol[r] * 8;
            wr[s][r][0] = *(const float4*)gw;
            wr[s][r][1] = *(const float4*)(gw + 4);
        }
    }

    f32x4 acc[2][4] = {};

    #pragma unroll
    for (int kt = 0; kt < 16; ++kt) {
        const int s = kt & 1;

        // write LDS[s] from regs loaded at kt-2 (or prologue)
        *(bf16x8*)&Xs[s][xoff] = cvt8(xr[s][0], xr[s][1]);
        #pragma unroll
        for (int r = 0; r < 8; ++r)
            *(bf16x8*)&Ws[s][woff[r]] = cvt8(wr[s][r][0], wr[s][r][1]);
        __syncthreads();   // single barrier per kt (R7-verified): writes to s
                           // visible; readers of s^1 (kt-1) lgkm-drained here;
                           // s^1 rewritten only at kt+1

        // issue global prefetch for kt+2 into stage s (regs now free)
        if (kt < 14) {
            const int k0 = (kt + 2) * 64;
            const float* gx = X + (size_t)(m0 + xrow) * DMODEL + k0 + xcol * 8;
            xr[s][0] = *(const float4*)gx;
            xr[s][1] = *(const float4*)(gx + 4);
            #pragma unroll
            for (int r = 0; r < 8; ++r) {
                const float* gw = W + (size_t)wrow[r] * DMODEL + k0 + wcol[r] * 8;
                wr[s][r][0] = *(const float4*)gw;
                wr[s][r][1] = *(const float4*)(gw + 4);
            }
        }

        // compute on LDS[s]
        #pragma unroll
        for (int ks = 0; ks < 2; ++ks) {
            const int ch = (((ks << 2) | quad) ^ swz) * 8;
            bf16x8 af[2], bfr[4];
            #pragma unroll
            for (int i = 0; i < 2; ++i)
                af[i] = *(const bf16x8*)&Xs[s][(i * 16 + l16) * 64 + ch];
            #pragma unroll
            for (int j = 0; j < 4; ++j)
                bfr[j] = *(const bf16x8*)&Ws[s][(wn + j * 16 + l16) * 64 + ch];
            #pragma unroll
            for (int i = 0; i < 2; ++i)
                #pragma unroll
                for (int j = 0; j < 4; ++j)
                    acc[i][j] = __builtin_amdgcn_mfma_f32_16x16x32_bf16(
                        af[i], bfr[j], acc[i][j], 0, 0, 0);
        }
    }

    #pragma unroll
    for (int i = 0; i < 2; ++i) {
        #pragma unroll
        for (int j = 0; j < 4; ++j) {
            const int gn = wn + j * 16 + l16;
            const float bv = bias[gn];
            #pragma unroll
            for (int r = 0; r < 4; ++r) {
                const int gm = m0 + i * 16 + quad * 4 + r;
                float v = acc[i][j][r] + bv;
                v = v > 0.f ? v : 0.f;
                H[(size_t)gm * DPROJ + gn] = (bf16_t)v;
            }
        }
    }
}

// ---------------------------------------------------------------------------
// Kernel 2 (R0 known-good, UNTOUCHED): Out[b,i,j] = scale*sum_p H[i,p]H[j,p]+off.
// 64x64 TRIANGULAR tiles: 528/batch, 2112 blocks, 256 thr, 16KB LDS ->
// 8 co-resident blocks/CU. Latency hidden by block TURNOVER (R1's 128^2
// L2-direct variant at 2.1 blocks/CU regressed +10.5us). ~11us vs 10.6us
// floor for the 67 MB Out store stream — at roofline, leave alone.
// ---------------------------------------------------------------------------
__global__ __launch_bounds__(256, 8) void score_kernel(
    const bf16_t* __restrict__ H, const float* __restrict__ clf_w,
    const float* __restrict__ clf_b, float* __restrict__ Out)
{
    __shared__ __align__(16) bf16_t As[64 * 64];   // 8 KB
    __shared__ __align__(16) bf16_t Bs[64 * 64];   // 8 KB

    // triangular decode: blockIdx.x in [0,528) -> (bi,bj), bi<=bj, T=32
    int t = blockIdx.x, bi = 0, rl = SEQ / 64;
    while (t >= rl) { t -= rl; --rl; ++bi; }
    const int bj = bi + t;
    const int b  = blockIdx.y;
    const int m0 = bi * 64;
    const int n0 = bj * 64;
    const bf16_t* Hb = H + (size_t)b * SEQ * DPROJ;
    float* Ob = Out + (size_t)b * SEQ * SEQ;

    const int tid  = threadIdx.x;
    const int lane = tid & 63;
    const int wave = tid >> 6;
    const int quad = lane >> 4;
    const int l16  = lane & 15;
    const int wm = (wave & 1) * 32;
    const int wn = (wave >> 1) * 32;
    const int swz = l16 & 7;

    // staging: 512 16B chunks per matrix per K-tile; instr t2 in {0,1}:
    // g = (wave*2+t2)*64 + lane; row = g>>3, stored chunk = (g&7)^(row&7)
    const bf16_t* gA[2];
    const bf16_t* gB[2];
    bf16_t* lA[2];
    bf16_t* lB[2];
    #pragma unroll
    for (int t2 = 0; t2 < 2; ++t2) {
        const int g   = (wave * 2 + t2) * 64 + lane;
        const int row = g >> 3;
        const int gc  = (g & 7) ^ (row & 7);
        gA[t2] = Hb + (size_t)(m0 + row) * DPROJ + gc * 8;
        gB[t2] = Hb + (size_t)(n0 + row) * DPROJ + gc * 8;
        lA[t2] = As + (wave * 2 + t2) * 512;
        lB[t2] = Bs + (wave * 2 + t2) * 512;
    }

    f32x4 acc[2][2] = {};

    for (int kt = 0; kt < 4; ++kt) {
        __syncthreads();
        #pragma unroll
        for (int t2 = 0; t2 < 2; ++t2) {
            gl_lds16(gA[t2], lA[t2]);
            gl_lds16(gB[t2], lB[t2]);
        }
        __syncthreads();               // drains vmcnt -> data visible
        #pragma unroll
        for (int t2 = 0; t2 < 2; ++t2) { gA[t2] += 64; gB[t2] += 64; }

        #pragma unroll
        for (int ks = 0; ks < 2; ++ks) {
            const int ch = (((ks << 2) | quad) ^ swz) * 8;
            bf16x8 af[2], bfr[2];
            #pragma unroll
            for (int i = 0; i < 2; ++i) {
                af[i]  = *(const bf16x8*)&As[(wm + i * 16 + l16) * 64 + ch];
                bfr[i] = *(const bf16x8*)&Bs[(wn + i * 16 + l16) * 64 + ch];
            }
            #pragma unroll
            for (int i = 0; i < 2; ++i)
                #pragma unroll
                for (int j = 0; j < 2; ++j)
                    acc[i][j] = __builtin_amdgcn_mfma_f32_16x16x32_bf16(
                        af[i], bfr[j], acc[i][j], 0, 0, 0);
        }
    }

    const float scale = clf_w[0];
    const float off   = clf_b[0];

    // direct tile (bi,bj)
    #pragma unroll
    for (int i = 0; i < 2; ++i)
        #pragma unroll
        for (int j = 0; j < 2; ++j)
            #pragma unroll
            for (int r = 0; r < 4; ++r) {
                const int gm = m0 + wm + i * 16 + quad * 4 + r;
                const int gn = n0 + wn + j * 16 + l16;
                Ob[(size_t)gm * SEQ + gn] = acc[i][j][r] * scale + off;
            }

    // mirror tile (bj,bi): row gn, 4 consecutive cols gm -> float4 store
    if (bi != bj) {
        #pragma unroll
        for (int i = 0; i < 2; ++i)
            #pragma unroll
            for (int j = 0; j < 2; ++j) {
                const int gn = n0 + wn + j * 16 + l16;
                const int gm = m0 + wm + i * 16 + quad * 4;
                float4 v;
                v.x = acc[i][j][0] * scale + off;
                v.y = acc[i][j][1] * scale + off;
                v.z = acc[i][j][2] * scale + off;
                v.w = acc[i][j][3] * scale + off;
                *(float4*)&Ob[(size_t)gn * SEQ + gm] = v;
            }
    }
}

extern "C" void kernel_launch(void* const* d_in, const int* in_sizes, int n_in,
                              void* d_out, int out_size, void* d_ws, size_t ws_size,
                              hipStream_t stream) {
    const float* X    = (const float*)d_in[0];  // [4,2048,1024]
    const float* W    = (const float*)d_in[1];  // [256,1024]
    const float* bias = (const float*)d_in[2];  // [256]
    const float* clfw = (const float*)d_in[3];  // [1,1]
    const float* clfb = (const float*)d_in[4];  // [1]
    float* Out = (float*)d_out;                 // [4,2048,2048]
    bf16_t* H  = (bf16_t*)d_ws;                 // [8192,256] bf16 = 4 MB

    dim3 g1(NBATCH * SEQ / 32, 1, 1);           // 256 blocks, 1/CU, X read once
    proj_kernel<<<g1, 256, 0, stream>>>(X, W, bias, H);

    const int ntile = SEQ / 64;                 // 32
    dim3 g2(ntile * (ntile + 1) / 2, NBATCH);   // 528 x 4 = 2112 blocks
    score_kernel<<<g2, 256, 0, stream>>>(H, clfw, clfb, Out);
}

// Round 10
// 122.744 us; speedup vs baseline: 1.0105x; 1.0105x over previous
//
#include <hip/hip_runtime.h>
#include <hip/hip_bf16.h>

typedef __bf16 bf16_t;
typedef __attribute__((ext_vector_type(8))) __bf16 bf16x8;
typedef __attribute__((ext_vector_type(4))) float f32x4;

#define SEQ    2048
#define DMODEL 1024
#define DPROJ  256
#define NBATCH 4

__device__ __forceinline__ bf16x8 cvt8(const float4& lo, const float4& hi) {
    bf16x8 v;
    v[0] = (bf16_t)lo.x; v[1] = (bf16_t)lo.y; v[2] = (bf16_t)lo.z; v[3] = (bf16_t)lo.w;
    v[4] = (bf16_t)hi.x; v[5] = (bf16_t)hi.y; v[6] = (bf16_t)hi.z; v[7] = (bf16_t)hi.w;
    return v;
}

// async global->LDS, 16 bytes per lane. LDS dest = wave-uniform base + lane*16.
__device__ __forceinline__ void gl_lds16(const void* g, void* l) {
    __builtin_amdgcn_global_load_lds(
        (const __attribute__((address_space(1))) unsigned int*)g,
        (__attribute__((address_space(3))) unsigned int*)l, 16, 0, 0);
}

// ---------------------------------------------------------------------------
// Kernel 1 v8: H[m,p] = relu(sum_d X[m,d]*W[p,d] + b[p]).
// TRAFFIC MODEL (fits R0/R4/R5/R9): proj is bound by total global-load bytes
// T = 33.5MB*numN (X via L3, ~2x redundant OK) + numM*1MB (W via L2) at
// ~11-12 TB/s effective. R0: 268MB->23us. R5: 402->+6.6. R9: 290->+2.5.
// Schedule experiments (R2,R7,R8) all neutral: they never changed T.
// THIS ROUND: minimize T at grid>=256: BM=64, BN=128 -> T = 67(X,L3) +
// 134(W,L2) = 201MB, grid 128x2=256 (1 block/CU; R9 showed 1/CU is fine).
// X-tile sharers (same m0) are 128 apart in dispatch, 128%8==0 -> same XCD.
// Template: R7/R8-verified single-__syncthreads dbuf, distance-2 prefetch.
// Geometry: 256 thr, 4 waves, wave-grid 2Mx2N: each wave 32x64 = 2x4 frags
// (32 acc VGPR). Staging/kt/thread: X 2 chunks + W 4 chunks; dist-2 regs =
// 24 float4 = 96 VGPR. LDS: X 2x8KB + W 2x16KB = 48 KB.
// ---------------------------------------------------------------------------
__global__ __launch_bounds__(256) void proj_kernel(
    const float* __restrict__ X, const float* __restrict__ W,
    const float* __restrict__ bias, bf16_t* __restrict__ H)
{
    __shared__ __align__(16) bf16_t Xs[2][64 * 64];    // 2 x 8 KB
    __shared__ __align__(16) bf16_t Ws[2][128 * 64];   // 2 x 16 KB

    const int m0 = blockIdx.x * 64;
    const int n0 = blockIdx.y * 128;
    const int tid  = threadIdx.x;
    const int lane = tid & 63;
    const int wave = tid >> 6;
    const int quad = lane >> 4;
    const int l16  = lane & 15;
    const int wm = (wave & 1) * 32;    // 2 M-halves
    const int wn = (wave >> 1) * 64;   // 2 N-halves (64 wide each)
    const int swz = l16 & 7;

    // X staging: 512 chunks (8 bf16 each), 2 per thread (R0 pattern)
    int xsrow[2], xscol[2], xsoff[2];
    #pragma unroll
    for (int r = 0; r < 2; ++r) {
        const int p = r * 256 + tid;
        xsrow[r] = p >> 3;             // 0..63
        xscol[r] = p & 7;
        xsoff[r] = xsrow[r] * 64 + ((xscol[r] ^ (xsrow[r] & 7)) * 8);
    }
    // W staging: 128x64 = 1024 chunks, 4 per thread
    int wsrow[4], wscol[4], wsoff[4];
    #pragma unroll
    for (int r = 0; r < 4; ++r) {
        const int p = r * 256 + tid;
        wsrow[r] = p >> 3;             // 0..127
        wscol[r] = p & 7;
        wsoff[r] = wsrow[r] * 64 + ((wscol[r] ^ (wsrow[r] & 7)) * 8);
    }

    float4 xr[2][2][2];    // [stage][r][half]
    float4 wr[2][4][2];    // [stage][r][half]

    // prologue: preload kt=0 and kt=1 (distance-2)
    #pragma unroll
    for (int s = 0; s < 2; ++s) {
        const int k0 = s * 64;
        #pragma unroll
        for (int r = 0; r < 2; ++r) {
            const float* gx = X + (size_t)(m0 + xsrow[r]) * DMODEL + k0 + xscol[r] * 8;
            xr[s][r][0] = *(const float4*)gx;
            xr[s][r][1] = *(const float4*)(gx + 4);
        }
        #pragma unroll
        for (int r = 0; r < 4; ++r) {
            const float* gw = W + (size_t)(n0 + wsrow[r]) * DMODEL + k0 + wscol[r] * 8;
            wr[s][r][0] = *(const float4*)gw;
            wr[s][r][1] = *(const float4*)(gw + 4);
        }
    }

    f32x4 acc[2][4] = {};

    #pragma unroll
    for (int kt = 0; kt < 16; ++kt) {
        const int s = kt & 1;

        // write LDS[s] from regs loaded at kt-2 (or prologue)
        #pragma unroll
        for (int r = 0; r < 2; ++r)
            *(bf16x8*)&Xs[s][xsoff[r]] = cvt8(xr[s][r][0], xr[s][r][1]);
        #pragma unroll
        for (int r = 0; r < 4; ++r)
            *(bf16x8*)&Ws[s][wsoff[r]] = cvt8(wr[s][r][0], wr[s][r][1]);
        __syncthreads();   // single barrier per kt (R7/R8-verified): writes to
                           // s visible; readers of s^1 (kt-1) lgkm-drained
                           // here; s^1 rewritten only at kt+1

        // issue global prefetch for kt+2 into stage s (regs now free)
        if (kt < 14) {
            const int k0 = (kt + 2) * 64;
            #pragma unroll
            for (int r = 0; r < 2; ++r) {
                const float* gx = X + (size_t)(m0 + xsrow[r]) * DMODEL + k0 + xscol[r] * 8;
                xr[s][r][0] = *(const float4*)gx;
                xr[s][r][1] = *(const float4*)(gx + 4);
            }
            #pragma unroll
            for (int r = 0; r < 4; ++r) {
                const float* gw = W + (size_t)(n0 + wsrow[r]) * DMODEL + k0 + wscol[r] * 8;
                wr[s][r][0] = *(const float4*)gw;
                wr[s][r][1] = *(const float4*)(gw + 4);
            }
        }

        // compute on LDS[s]
        #pragma unroll
        for (int ks = 0; ks < 2; ++ks) {
            const int ch = (((ks << 2) | quad) ^ swz) * 8;
            bf16x8 af[2], bfr[4];
            #pragma unroll
            for (int i = 0; i < 2; ++i)
                af[i] = *(const bf16x8*)&Xs[s][(wm + i * 16 + l16) * 64 + ch];
            #pragma unroll
            for (int j = 0; j < 4; ++j)
                bfr[j] = *(const bf16x8*)&Ws[s][(wn + j * 16 + l16) * 64 + ch];
            #pragma unroll
            for (int i = 0; i < 2; ++i)
                #pragma unroll
                for (int j = 0; j < 4; ++j)
                    acc[i][j] = __builtin_amdgcn_mfma_f32_16x16x32_bf16(
                        af[i], bfr[j], acc[i][j], 0, 0, 0);
        }
    }

    #pragma unroll
    for (int i = 0; i < 2; ++i) {
        #pragma unroll
        for (int j = 0; j < 4; ++j) {
            const int gn = n0 + wn + j * 16 + l16;
            const float bv = bias[gn];
            #pragma unroll
            for (int r = 0; r < 4; ++r) {
                const int gm = m0 + wm + i * 16 + quad * 4 + r;
                float v = acc[i][j][r] + bv;
                v = v > 0.f ? v : 0.f;
                H[(size_t)gm * DPROJ + gn] = (bf16_t)v;
            }
        }
    }
}

// ---------------------------------------------------------------------------
// Kernel 2 (R0 known-good, UNTOUCHED): Out[b,i,j] = scale*sum_p H[i,p]H[j,p]+off.
// 64x64 TRIANGULAR tiles: 528/batch, 2112 blocks, 256 thr, 16KB LDS ->
// 8 co-resident blocks/CU. Latency hidden by block TURNOVER (R1's 128^2
// L2-direct variant at 2.1 blocks/CU regressed +10.5us). ~11us vs 10.6us
// floor for the 67 MB Out store stream — at roofline, leave alone.
// ---------------------------------------------------------------------------
__global__ __launch_bounds__(256, 8) void score_kernel(
    const bf16_t* __restrict__ H, const float* __restrict__ clf_w,
    const float* __restrict__ clf_b, float* __restrict__ Out)
{
    __shared__ __align__(16) bf16_t As[64 * 64];   // 8 KB
    __shared__ __align__(16) bf16_t Bs[64 * 64];   // 8 KB

    // triangular decode: blockIdx.x in [0,528) -> (bi,bj), bi<=bj, T=32
    int t = blockIdx.x, bi = 0, rl = SEQ / 64;
    while (t >= rl) { t -= rl; --rl; ++bi; }
    const int bj = bi + t;
    const int b  = blockIdx.y;
    const int m0 = bi * 64;
    const int n0 = bj * 64;
    const bf16_t* Hb = H + (size_t)b * SEQ * DPROJ;
    float* Ob = Out + (size_t)b * SEQ * SEQ;

    const int tid  = threadIdx.x;
    const int lane = tid & 63;
    const int wave = tid >> 6;
    const int quad = lane >> 4;
    const int l16  = lane & 15;
    const int wm = (wave & 1) * 32;
    const int wn = (wave >> 1) * 32;
    const int swz = l16 & 7;

    // staging: 512 16B chunks per matrix per K-tile; instr t2 in {0,1}:
    // g = (wave*2+t2)*64 + lane; row = g>>3, stored chunk = (g&7)^(row&7)
    const bf16_t* gA[2];
    const bf16_t* gB[2];
    bf16_t* lA[2];
    bf16_t* lB[2];
    #pragma unroll
    for (int t2 = 0; t2 < 2; ++t2) {
        const int g   = (wave * 2 + t2) * 64 + lane;
        const int row = g >> 3;
        const int gc  = (g & 7) ^ (row & 7);
        gA[t2] = Hb + (size_t)(m0 + row) * DPROJ + gc * 8;
        gB[t2] = Hb + (size_t)(n0 + row) * DPROJ + gc * 8;
        lA[t2] = As + (wave * 2 + t2) * 512;
        lB[t2] = Bs + (wave * 2 + t2) * 512;
    }

    f32x4 acc[2][2] = {};

    for (int kt = 0; kt < 4; ++kt) {
        __syncthreads();
        #pragma unroll
        for (int t2 = 0; t2 < 2; ++t2) {
            gl_lds16(gA[t2], lA[t2]);
            gl_lds16(gB[t2], lB[t2]);
        }
        __syncthreads();               // drains vmcnt -> data visible
        #pragma unroll
        for (int t2 = 0; t2 < 2; ++t2) { gA[t2] += 64; gB[t2] += 64; }

        #pragma unroll
        for (int ks = 0; ks < 2; ++ks) {
            const int ch = (((ks << 2) | quad) ^ swz) * 8;
            bf16x8 af[2], bfr[2];
            #pragma unroll
            for (int i = 0; i < 2; ++i) {
                af[i]  = *(const bf16x8*)&As[(wm + i * 16 + l16) * 64 + ch];
                bfr[i] = *(const bf16x8*)&Bs[(wn + i * 16 + l16) * 64 + ch];
            }
            #pragma unroll
            for (int i = 0; i < 2; ++i)
                #pragma unroll
                for (int j = 0; j < 2; ++j)
                    acc[i][j] = __builtin_amdgcn_mfma_f32_16x16x32_bf16(
                        af[i], bfr[j], acc[i][j], 0, 0, 0);
        }
    }

    const float scale = clf_w[0];
    const float off   = clf_b[0];

    // direct tile (bi,bj)
    #pragma unroll
    for (int i = 0; i < 2; ++i)
        #pragma unroll
        for (int j = 0; j < 2; ++j)
            #pragma unroll
            for (int r = 0; r < 4; ++r) {
                const int gm = m0 + wm + i * 16 + quad * 4 + r;
                const int gn = n0 + wn + j * 16 + l16;
                Ob[(size_t)gm * SEQ + gn] = acc[i][j][r] * scale + off;
            }

    // mirror tile (bj,bi): row gn, 4 consecutive cols gm -> float4 store
    if (bi != bj) {
        #pragma unroll
        for (int i = 0; i < 2; ++i)
            #pragma unroll
            for (int j = 0; j < 2; ++j) {
                const int gn = n0 + wn + j * 16 + l16;
                const int gm = m0 + wm + i * 16 + quad * 4;
                float4 v;
                v.x = acc[i][j][0] * scale + off;
                v.y = acc[i][j][1] * scale + off;
                v.z = acc[i][j][2] * scale + off;
                v.w = acc[i][j][3] * scale + off;
                *(float4*)&Ob[(size_t)gn * SEQ + gm] = v;
            }
    }
}

extern "C" void kernel_launch(void* const* d_in, const int* in_sizes, int n_in,
                              void* d_out, int out_size, void* d_ws, size_t ws_size,
                              hipStream_t stream) {
    const float* X    = (const float*)d_in[0];  // [4,2048,1024]
    const float* W    = (const float*)d_in[1];  // [256,1024]
    const float* bias = (const float*)d_in[2];  // [256]
    const float* clfw = (const float*)d_in[3];  // [1,1]
    const float* clfb = (const float*)d_in[4];  // [1]
    float* Out = (float*)d_out;                 // [4,2048,2048]
    bf16_t* H  = (bf16_t*)d_ws;                 // [8192,256] bf16 = 4 MB

    dim3 g1(NBATCH * SEQ / 64, DPROJ / 128, 1); // 128 x 2 = 256 blocks
    proj_kernel<<<g1, 256, 0, stream>>>(X, W, bias, H);

    const int ntile = SEQ / 64;                 // 32
    dim3 g2(ntile * (ntile + 1) / 2, NBATCH);   // 528 x 4 = 2112 blocks
    score_kernel<<<g2, 256, 0, stream>>>(H, clfw, clfb, Out);
}

// Round 11
// 121.602 us; speedup vs baseline: 1.0200x; 1.0094x over previous
//
#include <hip/hip_runtime.h>
#include <hip/hip_bf16.h>

typedef __bf16 bf16_t;
typedef __attribute__((ext_vector_type(8))) __bf16 bf16x8;
typedef __attribute__((ext_vector_type(4))) float f32x4;

#define SEQ    2048
#define DMODEL 1024
#define DPROJ  256
#define NBATCH 4

__device__ __forceinline__ bf16x8 cvt8(const float4& lo, const float4& hi) {
    bf16x8 v;
    v[0] = (bf16_t)lo.x; v[1] = (bf16_t)lo.y; v[2] = (bf16_t)lo.z; v[3] = (bf16_t)lo.w;
    v[4] = (bf16_t)hi.x; v[5] = (bf16_t)hi.y; v[6] = (bf16_t)hi.z; v[7] = (bf16_t)hi.w;
    return v;
}

// async global->LDS, 16 bytes per lane. LDS dest = wave-uniform base + lane*16.
__device__ __forceinline__ void gl_lds16(const void* g, void* l) {
    __builtin_amdgcn_global_load_lds(
        (const __attribute__((address_space(1))) unsigned int*)g,
        (__attribute__((address_space(3))) unsigned int*)l, 16, 0, 0);
}

// ---------------------------------------------------------------------------
// Kernel 1 (FINAL, R7-verified best): H[m,p] = relu(sum_d X[m,d]*W[p,d]+b[p]).
// BM=BN=64, BK=64, 512 blocks, dbuf LDS, ONE __syncthreads/kt, distance-2
// VGPR prefetch. Measured 121.65 total (R7) == R0 anchor within noise.
// PLATEAU EVIDENCE (9 experiments, 0 wins):
//   schedule: raw-barrier dbuf +6 (and racy), single-sync dbuf neutral;
//   occupancy: BN=32 4/CU +6.6, (256,2) cap neutral, 1/CU variants +2.5;
//   geometry: BK=128 +9(grid-confounded), 32x256 +2.5, 64x128 neutral;
//   traffic: T 268->201MB (R10) zero delta -> not byte-bound either.
// X (33.5MB) is L3-resident; HBM component ~7us; residual time is invariant
// across 8-32 barriers, 1-2 blocks/CU, 201-402MB traffic -> dominated by
// fixed costs (launch/graph gaps + short-kernel pipeline fill), not by
// anything a kernel restructure reaches.
// ---------------------------------------------------------------------------
__global__ __launch_bounds__(256) void proj_kernel(
    const float* __restrict__ X, const float* __restrict__ W,
    const float* __restrict__ bias, bf16_t* __restrict__ H)
{
    __shared__ __align__(16) bf16_t Xs[2][64 * 64];   // 2 x 8 KB
    __shared__ __align__(16) bf16_t Ws[2][64 * 64];   // 2 x 8 KB

    const int m0 = blockIdx.x * 64;
    const int n0 = blockIdx.y * 64;
    const int tid  = threadIdx.x;
    const int lane = tid & 63;
    const int wave = tid >> 6;
    const int quad = lane >> 4;
    const int l16  = lane & 15;
    const int wm = (wave & 1) * 32;
    const int wn = (wave >> 1) * 32;
    const int swz = l16 & 7;

    int srow[2], scol[2], soff[2];
    #pragma unroll
    for (int r = 0; r < 2; ++r) {
        const int p = r * 256 + tid;
        srow[r] = p >> 3;
        scol[r] = p & 7;
        soff[r] = srow[r] * 64 + ((scol[r] ^ (srow[r] & 7)) * 8);
    }

    float4 xr[2][2][2], wr[2][2][2];   // [stage][r][half]

    // prologue: preload kt=0 and kt=1 (distance-2)
    #pragma unroll
    for (int s = 0; s < 2; ++s) {
        const int k0 = s * 64;
        #pragma unroll
        for (int r = 0; r < 2; ++r) {
            const float* gx = X + (size_t)(m0 + srow[r]) * DMODEL + k0 + scol[r] * 8;
            xr[s][r][0] = *(const float4*)gx;
            xr[s][r][1] = *(const float4*)(gx + 4);
            const float* gw = W + (size_t)(n0 + srow[r]) * DMODEL + k0 + scol[r] * 8;
            wr[s][r][0] = *(const float4*)gw;
            wr[s][r][1] = *(const float4*)(gw + 4);
        }
    }

    f32x4 acc[2][2] = {};

    #pragma unroll
    for (int kt = 0; kt < 16; ++kt) {
        const int s = kt & 1;

        // write LDS[s] from regs loaded at kt-2 (or prologue)
        #pragma unroll
        for (int r = 0; r < 2; ++r) {
            *(bf16x8*)&Xs[s][soff[r]] = cvt8(xr[s][r][0], xr[s][r][1]);
            *(bf16x8*)&Ws[s][soff[r]] = cvt8(wr[s][r][0], wr[s][r][1]);
        }
        __syncthreads();   // single barrier per kt: writes to s visible;
                           // readers of s^1 (kt-1) lgkm-drained here; s^1 is
                           // rewritten only at kt+1 -> race-free with plain
                           // __syncthreads only (verified R7/R8)

        // issue global prefetch for kt+2 into stage s (regs now free)
        if (kt < 14) {
            const int k0 = (kt + 2) * 64;
            #pragma unroll
            for (int r = 0; r < 2; ++r) {
                const float* gx = X + (size_t)(m0 + srow[r]) * DMODEL + k0 + scol[r] * 8;
                xr[s][r][0] = *(const float4*)gx;
                xr[s][r][1] = *(const float4*)(gx + 4);
                const float* gw = W + (size_t)(n0 + srow[r]) * DMODEL + k0 + scol[r] * 8;
                wr[s][r][0] = *(const float4*)gw;
                wr[s][r][1] = *(const float4*)(gw + 4);
            }
        }

        // compute on LDS[s]
        #pragma unroll
        for (int ks = 0; ks < 2; ++ks) {
            bf16x8 af[2], bfr[2];
            #pragma unroll
            for (int i = 0; i < 2; ++i) {
                const int ch = (((ks << 2) | quad) ^ swz) * 8;
                af[i]  = *(const bf16x8*)&Xs[s][(wm + i * 16 + l16) * 64 + ch];
                bfr[i] = *(const bf16x8*)&Ws[s][(wn + i * 16 + l16) * 64 + ch];
            }
            #pragma unroll
            for (int i = 0; i < 2; ++i)
                #pragma unroll
                for (int j = 0; j < 2; ++j)
                    acc[i][j] = __builtin_amdgcn_mfma_f32_16x16x32_bf16(
                        af[i], bfr[j], acc[i][j], 0, 0, 0);
        }
    }

    #pragma unroll
    for (int i = 0; i < 2; ++i) {
        #pragma unroll
        for (int j = 0; j < 2; ++j) {
            const int gn = n0 + wn + j * 16 + l16;
            const float bv = bias[gn];
            #pragma unroll
            for (int r = 0; r < 4; ++r) {
                const int gm = m0 + wm + i * 16 + quad * 4 + r;
                float v = acc[i][j][r] + bv;
                v = v > 0.f ? v : 0.f;
                H[(size_t)gm * DPROJ + gn] = (bf16_t)v;
            }
        }
    }
}

// ---------------------------------------------------------------------------
// Kernel 2 (FINAL, R0 known-good): Out[b,i,j] = scale*sum_p H[i,p]H[j,p]+off.
// 64x64 TRIANGULAR tiles: 528/batch, 2112 blocks, 256 thr, 16KB LDS ->
// 8 co-resident blocks/CU. Latency hidden by block TURNOVER (R1's 128^2
// L2-direct variant at 2.1 blocks/CU regressed +10.5us). ~11us vs 10.6us
// floor for the 67 MB Out store stream — at store roofline.
// ---------------------------------------------------------------------------
__global__ __launch_bounds__(256, 8) void score_kernel(
    const bf16_t* __restrict__ H, const float* __restrict__ clf_w,
    const float* __restrict__ clf_b, float* __restrict__ Out)
{
    __shared__ __align__(16) bf16_t As[64 * 64];   // 8 KB
    __shared__ __align__(16) bf16_t Bs[64 * 64];   // 8 KB

    // triangular decode: blockIdx.x in [0,528) -> (bi,bj), bi<=bj, T=32
    int t = blockIdx.x, bi = 0, rl = SEQ / 64;
    while (t >= rl) { t -= rl; --rl; ++bi; }
    const int bj = bi + t;
    const int b  = blockIdx.y;
    const int m0 = bi * 64;
    const int n0 = bj * 64;
    const bf16_t* Hb = H + (size_t)b * SEQ * DPROJ;
    float* Ob = Out + (size_t)b * SEQ * SEQ;

    const int tid  = threadIdx.x;
    const int lane = tid & 63;
    const int wave = tid >> 6;
    const int quad = lane >> 4;
    const int l16  = lane & 15;
    const int wm = (wave & 1) * 32;
    const int wn = (wave >> 1) * 32;
    const int swz = l16 & 7;

    // staging: 512 16B chunks per matrix per K-tile; instr t2 in {0,1}:
    // g = (wave*2+t2)*64 + lane; row = g>>3, stored chunk = (g&7)^(row&7)
    const bf16_t* gA[2];
    const bf16_t* gB[2];
    bf16_t* lA[2];
    bf16_t* lB[2];
    #pragma unroll
    for (int t2 = 0; t2 < 2; ++t2) {
        const int g   = (wave * 2 + t2) * 64 + lane;
        const int row = g >> 3;
        const int gc  = (g & 7) ^ (row & 7);
        gA[t2] = Hb + (size_t)(m0 + row) * DPROJ + gc * 8;
        gB[t2] = Hb + (size_t)(n0 + row) * DPROJ + gc * 8;
        lA[t2] = As + (wave * 2 + t2) * 512;
        lB[t2] = Bs + (wave * 2 + t2) * 512;
    }

    f32x4 acc[2][2] = {};

    for (int kt = 0; kt < 4; ++kt) {
        __syncthreads();
        #pragma unroll
        for (int t2 = 0; t2 < 2; ++t2) {
            gl_lds16(gA[t2], lA[t2]);
            gl_lds16(gB[t2], lB[t2]);
        }
        __syncthreads();               // drains vmcnt -> data visible
        #pragma unroll
        for (int t2 = 0; t2 < 2; ++t2) { gA[t2] += 64; gB[t2] += 64; }

        #pragma unroll
        for (int ks = 0; ks < 2; ++ks) {
            const int ch = (((ks << 2) | quad) ^ swz) * 8;
            bf16x8 af[2], bfr[2];
            #pragma unroll
            for (int i = 0; i < 2; ++i) {
                af[i]  = *(const bf16x8*)&As[(wm + i * 16 + l16) * 64 + ch];
                bfr[i] = *(const bf16x8*)&Bs[(wn + i * 16 + l16) * 64 + ch];
            }
            #pragma unroll
            for (int i = 0; i < 2; ++i)
                #pragma unroll
                for (int j = 0; j < 2; ++j)
                    acc[i][j] = __builtin_amdgcn_mfma_f32_16x16x32_bf16(
                        af[i], bfr[j], acc[i][j], 0, 0, 0);
        }
    }

    const float scale = clf_w[0];
    const float off   = clf_b[0];

    // direct tile (bi,bj)
    #pragma unroll
    for (int i = 0; i < 2; ++i)
        #pragma unroll
        for (int j = 0; j < 2; ++j)
            #pragma unroll
            for (int r = 0; r < 4; ++r) {
                const int gm = m0 + wm + i * 16 + quad * 4 + r;
                const int gn = n0 + wn + j * 16 + l16;
                Ob[(size_t)gm * SEQ + gn] = acc[i][j][r] * scale + off;
            }

    // mirror tile (bj,bi): row gn, 4 consecutive cols gm -> float4 store
    if (bi != bj) {
        #pragma unroll
        for (int i = 0; i < 2; ++i)
            #pragma unroll
            for (int j = 0; j < 2; ++j) {
                const int gn = n0 + wn + j * 16 + l16;
                const int gm = m0 + wm + i * 16 + quad * 4;
                float4 v;
                v.x = acc[i][j][0] * scale + off;
                v.y = acc[i][j][1] * scale + off;
                v.z = acc[i][j][2] * scale + off;
                v.w = acc[i][j][3] * scale + off;
                *(float4*)&Ob[(size_t)gn * SEQ + gm] = v;
            }
    }
}

extern "C" void kernel_launch(void* const* d_in, const int* in_sizes, int n_in,
                              void* d_out, int out_size, void* d_ws, size_t ws_size,
                              hipStream_t stream) {
    const float* X    = (const float*)d_in[0];  // [4,2048,1024]
    const float* W    = (const float*)d_in[1];  // [256,1024]
    const float* bias = (const float*)d_in[2];  // [256]
    const float* clfw = (const float*)d_in[3];  // [1,1]
    const float* clfb = (const float*)d_in[4];  // [1]
    float* Out = (float*)d_out;                 // [4,2048,2048]
    bf16_t* H  = (bf16_t*)d_ws;                 // [8192,256] bf16 = 4 MB

    dim3 g1(NBATCH * SEQ / 64, DPROJ / 64, 1);  // 128 x 4 = 512 blocks
    proj_kernel<<<g1, 256, 0, stream>>>(X, W, bias, H);

    const int ntile = SEQ / 64;                 // 32
    dim3 g2(ntile * (ntile + 1) / 2, NBATCH);   // 528 x 4 = 2112 blocks
    score_kernel<<<g2, 256, 0, stream>>>(H, clfw, clfb, Out);
}